// Round 8
// baseline (1593.866 us; speedup 1.0000x reference)
//
#include <hip/hip_runtime.h>

#define NPTS 6144
#define RESCALE (1.0f / 1024.0f)
#define NITER 10

// Triangle tiling: 48 tiles of 128 points, ib<=jb (1176 pairs).
// ONE persistent kernel (plain launch): 512 blocks x 256 thr, co-resident by
// construction (launch_bounds(256,2) -> >=2 blocks/CU x 256 CU = 512; LDS
// 25.6KB would allow 6/CU). NO grid barrier: per-tile dataflow flags.
// Iter k reads vbuf[k], atomics into vbuf[k+1] (11 pre-zeroed buffers).
// Producer sets flags[it][tile] (single writer, release); consumer polls the
// 96 prev-iter flags covering its two row-tiles (zero RMW contention -- the
// round-7 RMW barrier storm cost ~75us/iter).
#define NB   48
#define BT   128
#define NTILE (NB * (NB + 1) / 2)   // 1176
#define GRID  512
#define MI   2                      // row-tiles per wave (32 rows)
#define JT   8                      // j-tiles (128/16)
#define ROWU 12                     // u32/row: mult of 4 -> 16B-aligned b128
#define OFF_A3 (BT * ROWU)
#define OFF_B2 (2 * BT * ROWU)
#define OFF_B3 (3 * BT * ROWU)
#define OFF_VJ (4 * BT * ROWU)
#define OFF_VI (OFF_VJ + BT)
#define OFF_Z  (OFF_VJ + 2 * BT)    // 16B zero pad for kb==3 reads
#define LDS_U32 (OFF_Z + 4)         // 6404 u32 = 25616 B

#define VSTRIDE 8192                // floats per v-buffer slot
#define NVF ((NITER + 1) * VSTRIDE) // 90112 floats of v-buffers
#define NFLAG (NITER * NTILE)       // 11760 flags

typedef unsigned short u16;
typedef unsigned int   u32;
typedef float v2f    __attribute__((ext_vector_type(2)));
typedef short bf16x8 __attribute__((ext_vector_type(8)));
typedef float f32x4  __attribute__((ext_vector_type(4)));

__device__ __forceinline__ u16 bsplit(float& x) {
  u32 u = __float_as_uint(x) & 0xFFFF0000u;
  x -= __uint_as_float(u);
  return (u16)(u >> 16);
}
__device__ __forceinline__ u32 pk(u16 lo, u16 hi) { return (u32)lo | ((u32)hi << 16); }

// Fragment packing (HW-verified rounds 2-4/7, absmax 6.1e-5):
//   a(i,j) = n2_i + n2_j - 2<p2_i,p2_j> via 3-way bf16 splits (K=18 of 32),
//   b(i,j) likewise for 3D (K=24 of 32). Slots 12..15 are implicit zeros.
__device__ __forceinline__ void build_i(float x2, float y2, float x3, float y3,
                                        float z3, u32* __restrict__ a2,
                                        u32* __restrict__ a3) {
  float n2 = fmaf(x2, x2, y2 * y2);
  float n3 = fmaf(x3, x3, fmaf(y3, y3, z3 * z3));
  const u16 ONE = 0x3F80;
  float t;
  t = -2.f * x2; u16 AXH = bsplit(t), AXM = bsplit(t), AXL = bsplit(t);
  t = -2.f * y2; u16 AYH = bsplit(t), AYM = bsplit(t), AYL = bsplit(t);
  t = n2;        u16 N2H = bsplit(t), N2M = bsplit(t), N2L = bsplit(t);
  t = -2.f * x3; u16 CXH = bsplit(t), CXM = bsplit(t), CXL = bsplit(t);
  t = -2.f * y3; u16 CYH = bsplit(t), CYM = bsplit(t), CYL = bsplit(t);
  t = -2.f * z3; u16 CZH = bsplit(t), CZM = bsplit(t), CZL = bsplit(t);
  t = n3;        u16 N3H = bsplit(t), N3M = bsplit(t), N3L = bsplit(t);
  a2[0] = pk(AXH, AYH); a2[1] = pk(AXM, AYM); a2[2] = pk(AXH, AYH); a2[3] = pk(AXM, AYM);
  a2[4] = pk(AXL, AYL); a2[5] = pk(AXH, AYH); a2[6] = pk(N2H, N2M); a2[7] = pk(N2L, ONE);
  a2[8] = pk(ONE, ONE); a2[9] = 0u; a2[10] = 0u; a2[11] = 0u;
  a3[0] = pk(CXH, CYH); a3[1]  = pk(CZH, CXM); a3[2]  = pk(CYM, CZM); a3[3]  = pk(CXH, CYH);
  a3[4] = pk(CZH, CXM); a3[5]  = pk(CYM, CZM); a3[6]  = pk(CXL, CYL); a3[7]  = pk(CZL, CXH);
  a3[8] = pk(CYH, CZH); a3[9]  = pk(N3H, N3M); a3[10] = pk(N3L, ONE); a3[11] = pk(ONE, ONE);
}

__device__ __forceinline__ void build_j(float x2, float y2, float x3, float y3,
                                        float z3, u32* __restrict__ b2,
                                        u32* __restrict__ b3) {
  float n2 = fmaf(x2, x2, y2 * y2);
  float n3 = fmaf(x3, x3, fmaf(y3, y3, z3 * z3));
  const u16 ONE = 0x3F80;
  float t;
  t = x2; u16 BXH = bsplit(t), BXM = bsplit(t), BXL = bsplit(t);
  t = y2; u16 BYH = bsplit(t), BYM = bsplit(t), BYL = bsplit(t);
  t = n2; u16 N2H = bsplit(t), N2M = bsplit(t), N2L = bsplit(t);
  t = x3; u16 DXH = bsplit(t), DXM = bsplit(t), DXL = bsplit(t);
  t = y3; u16 DYH = bsplit(t), DYM = bsplit(t), DYL = bsplit(t);
  t = z3; u16 DZH = bsplit(t), DZM = bsplit(t), DZL = bsplit(t);
  t = n3; u16 N3H = bsplit(t), N3M = bsplit(t), N3L = bsplit(t);
  b2[0] = pk(BXH, BYH); b2[1] = pk(BXH, BYH); b2[2] = pk(BXM, BYM); b2[3] = pk(BXM, BYM);
  b2[4] = pk(BXH, BYH); b2[5] = pk(BXL, BYL); b2[6] = pk(ONE, ONE); b2[7] = pk(ONE, N2H);
  b2[8] = pk(N2M, N2L); b2[9] = 0u; b2[10] = 0u; b2[11] = 0u;
  b3[0] = pk(DXH, DYH); b3[1]  = pk(DZH, DXH); b3[2]  = pk(DYH, DZH); b3[3]  = pk(DXM, DYM);
  b3[4] = pk(DZM, DXM); b3[5]  = pk(DYM, DZM); b3[6]  = pk(DXH, DYH); b3[7]  = pk(DZH, DXL);
  b3[8] = pk(DYL, DZL); b3[9]  = pk(ONE, ONE); b3[10] = pk(ONE, N3H); b3[11] = pk(N3M, N3L);
}

// Init all 11 v-buffers (buf0 = ones, rest zero) and all flags. Runs each
// graph replay -> whole pipeline idempotent.
__global__ __launch_bounds__(256) void prep_kernel(float* __restrict__ vbase,
                                                   u32* __restrict__ flags) {
  const int idx = blockIdx.x * 256 + threadIdx.x;
  if (idx < NVF) vbase[idx] = (idx < VSTRIDE) ? 1.0f : 0.0f;
  const int f = idx - NVF;
  if (f >= 0 && f < NFLAG) flags[f] = 0u;
}

__global__ __launch_bounds__(256, 2) void sc2_kernel(
    const float* __restrict__ p2, const float* __restrict__ p3,
    float* __restrict__ vbase, u32* __restrict__ flags,
    float* __restrict__ out) {
  __shared__ u32 sh[LDS_U32];
  float* shf = (float*)sh;

  const int bid  = blockIdx.x;
  const int t    = threadIdx.x;
  const int lane = t & 63;
  const int wv   = t >> 6;
  const int col  = lane & 15;
  const int kb   = lane >> 4;
  const int kb4  = kb * 4;
  const bool k3  = (kb == 3);

  if (t < 4) sh[OFF_Z + t] = 0u;   // LDS zero pad for kb==3 fragment reads

  const v2f kM100 = (v2f){-100.0f, -100.0f};
  const v2f k200  = (v2f){ 200.0f,  200.0f};
  const v2f kOne  = (v2f){   1.0f,    1.0f};
  const v2f kZero = (v2f){   0.0f,    0.0f};
  const f32x4 z4  = (f32x4){0.f, 0.f, 0.f, 0.f};

  for (int it = 0; it < NITER; ++it) {
    const float* vsrc = vbase + it * VSTRIDE;
    float* vdst = vbase + (it + 1) * VSTRIDE;
    const u32* fprev = flags + (it - 1) * NTILE;   // valid when it > 0
    u32* fcur = flags + it * NTILE;

    for (int tl = bid; tl < NTILE; tl += GRID) {
      // Triangle decode: tl -> (ib <= jb);  tidx(a<=b) = b*(b+1)/2 + a
      int r = (int)((sqrtf(8.f * (float)tl + 1.f) - 1.f) * 0.5f);
      while ((r + 1) * (r + 2) / 2 <= tl) ++r;
      while (r * (r + 1) / 2 > tl) --r;
      const int ib = tl - r * (r + 1) / 2;
      const int jb = r;
      const bool offd = (ib != jb);

      // WAIT: all prev-iter tiles touching rows ib and jb must be done.
      if (it > 0) {
        int ok;
        do {
          int mine = 1;
          if (t < NB) {
            const int x = t, a = min(ib, x), b = max(ib, x);
            mine = (__hip_atomic_load(&fprev[b * (b + 1) / 2 + a],
                                      __ATOMIC_RELAXED,
                                      __HIP_MEMORY_SCOPE_AGENT) != 0u);
          } else if (t >= 64 && t < 64 + NB) {
            const int x = t - 64, a = min(jb, x), b = max(jb, x);
            mine = (__hip_atomic_load(&fprev[b * (b + 1) / 2 + a],
                                      __ATOMIC_RELAXED,
                                      __HIP_MEMORY_SCOPE_AGENT) != 0u);
          }
          ok = __syncthreads_and(mine);
          if (!ok) __builtin_amdgcn_s_sleep(1);
        } while (!ok);
        __threadfence();   // acquire: L1 invalidate -> fresh vsrc reads
      }

      __syncthreads();   // previous tile's LDS readers done (also after poll)
      if (t < BT) {      // waves 0-1: i-side fragments + v_i
        const int ip = ib * BT + t;
        float x2 = p2[2 * ip], y2 = p2[2 * ip + 1];
        float x3 = p3[3 * ip], y3 = p3[3 * ip + 1], z3 = p3[3 * ip + 2];
        build_i(x2, y2, x3, y3, z3, &sh[t * ROWU], &sh[OFF_A3 + t * ROWU]);
        shf[OFF_VI + t] = vsrc[ip];
      } else {           // waves 2-3: j-side fragments + v_j
        const int tt = t - BT;
        const int jp = jb * BT + tt;
        float x2 = p2[2 * jp], y2 = p2[2 * jp + 1];
        float x3 = p3[3 * jp], y3 = p3[3 * jp + 1], z3 = p3[3 * jp + 2];
        build_j(x2, y2, x3, y3, z3, &sh[OFF_B2 + tt * ROWU],
                &sh[OFF_B3 + tt * ROWU]);
        shf[OFF_VJ + tt] = vsrc[jp];
      }
      __syncthreads();

      // A-fragments + v_i pairs to registers (kb==3 lanes read the zero pad).
      bf16x8 a2f[MI], a3f[MI];
      v2f vi2[MI][2];
#pragma unroll
      for (int mi = 0; mi < MI; ++mi) {
        const int rr = wv * 32 + mi * 16 + col;
        a2f[mi] = *(const bf16x8*)&sh[k3 ? OFF_Z : (rr * ROWU + kb4)];
        a3f[mi] = *(const bf16x8*)&sh[k3 ? OFF_Z : (OFF_A3 + rr * ROWU + kb4)];
#pragma unroll
        for (int p = 0; p < 2; ++p) {
          const int re = wv * 32 + mi * 16 + kb4 + 2 * p;
          vi2[mi][p] = (v2f){shf[OFF_VI + re], shf[OFF_VI + re + 1]};
        }
      }

      v2f racc[MI][2];
#pragma unroll
      for (int mi = 0; mi < MI; ++mi) {
        racc[mi][0] = (v2f){0.f, 0.f};
        racc[mi][1] = (v2f){0.f, 0.f};
      }

#pragma unroll
      for (int tj = 0; tj < JT; ++tj) {
        const int jrow = tj * 16 + col;
        const bf16x8 b2f = *(const bf16x8*)&sh[k3 ? OFF_Z : (OFF_B2 + jrow * ROWU + kb4)];
        const bf16x8 b3f = *(const bf16x8*)&sh[k3 ? OFF_Z : (OFF_B3 + jrow * ROWU + kb4)];
        const float vjs = shf[OFF_VJ + jrow];
        const v2f vj2 = (v2f){vjs, vjs};
        v2f cacc = (v2f){0.f, 0.f};
#pragma unroll
        for (int mi = 0; mi < MI; ++mi) {
          f32x4 aacc = __builtin_amdgcn_mfma_f32_16x16x32_bf16(a2f[mi], b2f, z4, 0, 0, 0);
          f32x4 bacc = __builtin_amdgcn_mfma_f32_16x16x32_bf16(a3f[mi], b3f, z4, 0, 0, 0);
#pragma unroll
          for (int p = 0; p < 2; ++p) {
            v2f a = (v2f){aacc[2 * p], aacc[2 * p + 1]};
            v2f b = (v2f){bacc[2 * p], bacc[2 * p + 1]};
            v2f ab = __builtin_elementwise_max(a * b, kZero);  // NaN guard near diag
            v2f s  = (v2f){__builtin_amdgcn_sqrtf(ab.x), __builtin_amdgcn_sqrtf(ab.y)};
            v2f w  = __builtin_elementwise_fma(a + b, kM100, kOne);
            w = __builtin_elementwise_fma(s, k200, w);
            w = __builtin_elementwise_max(w, kZero);
            racc[mi][p] = __builtin_elementwise_fma(w, vj2, racc[mi][p]);
            if (offd) cacc = __builtin_elementwise_fma(w, vi2[mi][p], cacc);
          }
        }
        if (offd) {  // column contribution: y[J] += S^T v_I (S symmetric)
          float c = cacc.x + cacc.y;
          c += __shfl_xor(c, 16);
          c += __shfl_xor(c, 32);
          if (lane < 16) atomicAdd(&vdst[jb * BT + tj * 16 + lane], c * RESCALE);
        }
      }

      // Row contribution: reduce across 16 columns, one atomic per row.
#pragma unroll
      for (int mi = 0; mi < MI; ++mi) {
#pragma unroll
        for (int p = 0; p < 2; ++p) {
          float r0 = racc[mi][p].x, r1 = racc[mi][p].y;
          r0 += __shfl_xor(r0, 1); r0 += __shfl_xor(r0, 2);
          r0 += __shfl_xor(r0, 4); r0 += __shfl_xor(r0, 8);
          r1 += __shfl_xor(r1, 1); r1 += __shfl_xor(r1, 2);
          r1 += __shfl_xor(r1, 4); r1 += __shfl_xor(r1, 8);
          if (col == 0) {
            const int row = ib * BT + wv * 32 + mi * 16 + kb4 + 2 * p;
            atomicAdd(&vdst[row],     r0 * RESCALE);
            atomicAdd(&vdst[row + 1], r1 * RESCALE);
          }
        }
      }

      // SIGNAL: this tile's atomics are durable, then one release store.
      __threadfence();     // each thread drains its own atomics
      __syncthreads();     // all threads drained
      if (t == 0)
        __hip_atomic_store(&fcur[tl], 1u, __ATOMIC_RELEASE,
                           __HIP_MEMORY_SCOPE_AGENT);
    }
  }

  // Finalize: blocks 0..23 wait for ALL iter-9 tiles, then normalize.
  if (bid < NPTS / 256) {
    const u32* f9 = flags + (NITER - 1) * NTILE;
    int ok;
    do {
      int mine = 1;
      for (int k2 = t; k2 < NTILE; k2 += 256)
        mine &= (__hip_atomic_load(&f9[k2], __ATOMIC_RELAXED,
                                   __HIP_MEMORY_SCOPE_AGENT) != 0u) ? 1 : 0;
      ok = __syncthreads_and(mine);
      if (!ok) __builtin_amdgcn_s_sleep(1);
    } while (!ok);
    __threadfence();

    const float* va = vbase + NITER * VSTRIDE;
    float ss = 0.0f;
    for (int k2 = t; k2 < NPTS; k2 += 256) {
      float x = va[k2];
      ss = fmaf(x, x, ss);
    }
    for (int off = 32; off > 0; off >>= 1) ss += __shfl_down(ss, off, 64);
    __syncthreads();
    if ((t & 63) == 0) shf[t >> 6] = ss;
    __syncthreads();
    float tot = shf[0] + shf[1] + shf[2] + shf[3];
    float inv = 1.0f / (sqrtf(tot) + 1e-6f);
    const int i = bid * 256 + t;
    out[i] = va[i] * inv;
  }
}

extern "C" void kernel_launch(void* const* d_in, const int* in_sizes, int n_in,
                              void* d_out, int out_size, void* d_ws, size_t ws_size,
                              hipStream_t stream) {
  const float* p2 = (const float*)d_in[0];   // 6144 x 2, float32
  const float* p3 = (const float*)d_in[1];   // 6144 x 3, float32
  float* out = (float*)d_out;                // 6144, float32

  float* w = (float*)d_ws;
  float* vbase = w;                          // 11 x 8192 floats
  u32*   flags = (u32*)(w + NVF);            // 10 x 1176 flags

  const int prep_elems = NVF + NFLAG;
  prep_kernel<<<(prep_elems + 255) / 256, 256, 0, stream>>>(vbase, flags);
  sc2_kernel<<<GRID, 256, 0, stream>>>(p2, p3, vbase, flags, out);
}

// Round 9
// 981.025 us; speedup vs baseline: 1.6247x; 1.6247x over previous
//
#include <hip/hip_runtime.h>

#define NPTS 6144
#define RESCALE (1.0f / 1024.0f)
#define NITER 10

// Triangle tiling: 48 tiles of 128 points, ib<=jb -> 1176 pairs = 2 per block.
// ONE persistent kernel: 588 blocks x 256 thr, co-resident by construction
// (launch_bounds(256,3) -> 3 blocks/CU x 256 CU = 768 >= 588; LDS 49.2KB x 3
// <= 160KB). Fragments built ONCE into LDS, reused all 10 iterations.
// Iteration barrier = signal-by-store (1 release store/block, no RMW) +
// wait-by-scan (each block scans 588 flags) -- kills round 7's 75us/iter
// RMW convoy and round 8's per-tile poll storm.
#define NB   48
#define BT   128
#define NTILE 1176
#define GRID  588
#define MI   2                      // row-tiles per wave (32 rows)
#define JT   8                      // j-tiles (128/16)
#define ROWU 12                     // u32/row: mult of 4 -> 16B-aligned b128
#define SLOT (4 * BT * ROWU)        // 6144 u32 per tile slot (A2|A3|B2|B3)
#define OFF_Z (2 * SLOT)            // 16B zero pad for kb==3 reads
#define LDS_U32 (OFF_Z + 4)         // 12292 u32 = 49168 B

#define VSTRIDE 8192                // floats per v-buffer slot
#define NVF ((NITER + 1) * VSTRIDE) // 11 pre-zeroed v-buffers
#define FSTRIDE 640                 // flag slots per iteration (>= GRID)
#define NFLAG (NITER * FSTRIDE)

typedef unsigned short u16;
typedef unsigned int   u32;
typedef float v2f    __attribute__((ext_vector_type(2)));
typedef short bf16x8 __attribute__((ext_vector_type(8)));
typedef float f32x4  __attribute__((ext_vector_type(4)));

__device__ __forceinline__ u16 bsplit(float& x) {
  u32 u = __float_as_uint(x) & 0xFFFF0000u;
  x -= __uint_as_float(u);
  return (u16)(u >> 16);
}
__device__ __forceinline__ u32 pk(u16 lo, u16 hi) { return (u32)lo | ((u32)hi << 16); }

// Fragment packing (HW-verified rounds 2-4/7/8, absmax 6.1e-5):
//   a(i,j) = n2_i + n2_j - 2<p2_i,p2_j> via 3-way bf16 splits (K=18 of 32),
//   b(i,j) likewise for 3D (K=24 of 32). Slots 12..15 are implicit zeros.
__device__ __forceinline__ void build_i(float x2, float y2, float x3, float y3,
                                        float z3, u32* __restrict__ a2,
                                        u32* __restrict__ a3) {
  float n2 = fmaf(x2, x2, y2 * y2);
  float n3 = fmaf(x3, x3, fmaf(y3, y3, z3 * z3));
  const u16 ONE = 0x3F80;
  float t;
  t = -2.f * x2; u16 AXH = bsplit(t), AXM = bsplit(t), AXL = bsplit(t);
  t = -2.f * y2; u16 AYH = bsplit(t), AYM = bsplit(t), AYL = bsplit(t);
  t = n2;        u16 N2H = bsplit(t), N2M = bsplit(t), N2L = bsplit(t);
  t = -2.f * x3; u16 CXH = bsplit(t), CXM = bsplit(t), CXL = bsplit(t);
  t = -2.f * y3; u16 CYH = bsplit(t), CYM = bsplit(t), CYL = bsplit(t);
  t = -2.f * z3; u16 CZH = bsplit(t), CZM = bsplit(t), CZL = bsplit(t);
  t = n3;        u16 N3H = bsplit(t), N3M = bsplit(t), N3L = bsplit(t);
  a2[0] = pk(AXH, AYH); a2[1] = pk(AXM, AYM); a2[2] = pk(AXH, AYH); a2[3] = pk(AXM, AYM);
  a2[4] = pk(AXL, AYL); a2[5] = pk(AXH, AYH); a2[6] = pk(N2H, N2M); a2[7] = pk(N2L, ONE);
  a2[8] = pk(ONE, ONE); a2[9] = 0u; a2[10] = 0u; a2[11] = 0u;
  a3[0] = pk(CXH, CYH); a3[1]  = pk(CZH, CXM); a3[2]  = pk(CYM, CZM); a3[3]  = pk(CXH, CYH);
  a3[4] = pk(CZH, CXM); a3[5]  = pk(CYM, CZM); a3[6]  = pk(CXL, CYL); a3[7]  = pk(CZL, CXH);
  a3[8] = pk(CYH, CZH); a3[9]  = pk(N3H, N3M); a3[10] = pk(N3L, ONE); a3[11] = pk(ONE, ONE);
}

__device__ __forceinline__ void build_j(float x2, float y2, float x3, float y3,
                                        float z3, u32* __restrict__ b2,
                                        u32* __restrict__ b3) {
  float n2 = fmaf(x2, x2, y2 * y2);
  float n3 = fmaf(x3, x3, fmaf(y3, y3, z3 * z3));
  const u16 ONE = 0x3F80;
  float t;
  t = x2; u16 BXH = bsplit(t), BXM = bsplit(t), BXL = bsplit(t);
  t = y2; u16 BYH = bsplit(t), BYM = bsplit(t), BYL = bsplit(t);
  t = n2; u16 N2H = bsplit(t), N2M = bsplit(t), N2L = bsplit(t);
  t = x3; u16 DXH = bsplit(t), DXM = bsplit(t), DXL = bsplit(t);
  t = y3; u16 DYH = bsplit(t), DYM = bsplit(t), DYL = bsplit(t);
  t = z3; u16 DZH = bsplit(t), DZM = bsplit(t), DZL = bsplit(t);
  t = n3; u16 N3H = bsplit(t), N3M = bsplit(t), N3L = bsplit(t);
  b2[0] = pk(BXH, BYH); b2[1] = pk(BXH, BYH); b2[2] = pk(BXM, BYM); b2[3] = pk(BXM, BYM);
  b2[4] = pk(BXH, BYH); b2[5] = pk(BXL, BYL); b2[6] = pk(ONE, ONE); b2[7] = pk(ONE, N2H);
  b2[8] = pk(N2M, N2L); b2[9] = 0u; b2[10] = 0u; b2[11] = 0u;
  b3[0] = pk(DXH, DYH); b3[1]  = pk(DZH, DXH); b3[2]  = pk(DYH, DZH); b3[3]  = pk(DXM, DYM);
  b3[4] = pk(DZM, DXM); b3[5]  = pk(DYM, DZM); b3[6]  = pk(DXH, DYH); b3[7]  = pk(DZH, DXL);
  b3[8] = pk(DYL, DZL); b3[9]  = pk(ONE, ONE); b3[10] = pk(ONE, N3H); b3[11] = pk(N3M, N3L);
}

// Init 11 v-buffers (buf0 = ones, rest zero -- atomic targets) and all
// flags. Runs each graph replay -> pipeline idempotent.
__global__ __launch_bounds__(256) void prep_kernel(float* __restrict__ vbase,
                                                   u32* __restrict__ flags) {
  const int idx = blockIdx.x * 256 + threadIdx.x;
  if (idx < NVF) vbase[idx] = (idx < VSTRIDE) ? 1.0f : 0.0f;
  const int f = idx - NVF;
  if (f >= 0 && f < NFLAG) flags[f] = 0u;
}

// Wait until all GRID blocks have signaled iteration `f[]`, then acquire.
__device__ __forceinline__ void wait_iter(const u32* __restrict__ f) {
  int ok;
  do {
    int mine = 1;
    for (int q = threadIdx.x; q < GRID; q += 256)
      mine &= (__hip_atomic_load(&f[q], __ATOMIC_RELAXED,
                                 __HIP_MEMORY_SCOPE_AGENT) != 0u) ? 1 : 0;
    ok = __syncthreads_and(mine);
    if (!ok) __builtin_amdgcn_s_sleep(2);
  } while (!ok);
  __threadfence();   // agent acquire: L1/L2 invalidate -> fresh v reads
}

__global__ __launch_bounds__(256, 3) void sc2_kernel(
    const float* __restrict__ p2, const float* __restrict__ p3,
    float* __restrict__ vbase, u32* __restrict__ flags,
    float* __restrict__ out) {
  __shared__ u32 sh[LDS_U32];
  float* shf = (float*)sh;

  const int bid  = blockIdx.x;
  const int t    = threadIdx.x;
  const int lane = t & 63;
  const int wv   = t >> 6;
  const int col  = lane & 15;
  const int kb   = lane >> 4;
  const int kb4  = kb * 4;
  const bool k3  = (kb == 3);

  if (t < 4) sh[OFF_Z + t] = 0u;   // zero pad for kb==3 fragment reads

  // Decode this block's two tiles (tl = bid and bid+GRID; 2*588 = 1176).
  int ibs[2], jbs[2];
#pragma unroll
  for (int s = 0; s < 2; ++s) {
    const int tl = bid + s * GRID;
    int r = (int)((sqrtf(8.f * (float)tl + 1.f) - 1.f) * 0.5f);
    while ((r + 1) * (r + 2) / 2 <= tl) ++r;
    while (r * (r + 1) / 2 > tl) --r;
    ibs[s] = tl - r * (r + 1) / 2;
    jbs[s] = r;
  }

  // Build fragments for BOTH tiles ONCE (reused all 10 iterations).
#pragma unroll
  for (int s = 0; s < 2; ++s) {
    const int base = s * SLOT;
    if (t < BT) {
      const int ip = ibs[s] * BT + t;
      float x2 = p2[2 * ip], y2 = p2[2 * ip + 1];
      float x3 = p3[3 * ip], y3 = p3[3 * ip + 1], z3 = p3[3 * ip + 2];
      build_i(x2, y2, x3, y3, z3, &sh[base + t * ROWU],
              &sh[base + BT * ROWU + t * ROWU]);
    } else {
      const int tt = t - BT;
      const int jp = jbs[s] * BT + tt;
      float x2 = p2[2 * jp], y2 = p2[2 * jp + 1];
      float x3 = p3[3 * jp], y3 = p3[3 * jp + 1], z3 = p3[3 * jp + 2];
      build_j(x2, y2, x3, y3, z3, &sh[base + 2 * BT * ROWU + tt * ROWU],
              &sh[base + 3 * BT * ROWU + tt * ROWU]);
    }
  }
  __syncthreads();

  // Hoist A-side fragments for both tiles to registers.
  bf16x8 a2f[2][MI], a3f[2][MI];
#pragma unroll
  for (int s = 0; s < 2; ++s)
#pragma unroll
    for (int mi = 0; mi < MI; ++mi) {
      const int rr = wv * 32 + mi * 16 + col;
      a2f[s][mi] = *(const bf16x8*)&sh[k3 ? OFF_Z : (s * SLOT + rr * ROWU + kb4)];
      a3f[s][mi] = *(const bf16x8*)&sh[k3 ? OFF_Z : (s * SLOT + BT * ROWU + rr * ROWU + kb4)];
    }

  const v2f kM100 = (v2f){-100.0f, -100.0f};
  const v2f k200  = (v2f){ 200.0f,  200.0f};
  const v2f kOne  = (v2f){   1.0f,    1.0f};
  const v2f kZero = (v2f){   0.0f,    0.0f};
  const f32x4 z4  = (f32x4){0.f, 0.f, 0.f, 0.f};

  for (int it = 0; it < NITER; ++it) {
    const float* vsrc = vbase + it * VSTRIDE;
    float* vdst = vbase + (it + 1) * VSTRIDE;
    if (it > 0) wait_iter(flags + (it - 1) * FSTRIDE);

#pragma unroll
    for (int s = 0; s < 2; ++s) {
      const int ib = ibs[s], jb = jbs[s];
      const bool offd = (ib != jb);
      const int i0 = ib * BT, j0 = jb * BT;

      // v_i pairs straight from global (plain loads, post-fence: proven r7/r8)
      v2f vi2[MI][2];
#pragma unroll
      for (int mi = 0; mi < MI; ++mi)
#pragma unroll
        for (int p = 0; p < 2; ++p) {
          const int re = wv * 32 + mi * 16 + kb4 + 2 * p;
          vi2[mi][p] = (v2f){vsrc[i0 + re], vsrc[i0 + re + 1]};
        }

      v2f racc[MI][2];
#pragma unroll
      for (int mi = 0; mi < MI; ++mi) {
        racc[mi][0] = (v2f){0.f, 0.f};
        racc[mi][1] = (v2f){0.f, 0.f};
      }

#pragma unroll
      for (int tj = 0; tj < JT; ++tj) {
        const int jrow = tj * 16 + col;
        const bf16x8 b2f = *(const bf16x8*)&sh[k3 ? OFF_Z : (s * SLOT + 2 * BT * ROWU + jrow * ROWU + kb4)];
        const bf16x8 b3f = *(const bf16x8*)&sh[k3 ? OFF_Z : (s * SLOT + 3 * BT * ROWU + jrow * ROWU + kb4)];
        const float vjs = vsrc[j0 + jrow];
        const v2f vj2 = (v2f){vjs, vjs};
        v2f cacc = (v2f){0.f, 0.f};
#pragma unroll
        for (int mi = 0; mi < MI; ++mi) {
          f32x4 aacc = __builtin_amdgcn_mfma_f32_16x16x32_bf16(a2f[s][mi], b2f, z4, 0, 0, 0);
          f32x4 bacc = __builtin_amdgcn_mfma_f32_16x16x32_bf16(a3f[s][mi], b3f, z4, 0, 0, 0);
#pragma unroll
          for (int p = 0; p < 2; ++p) {
            v2f a = (v2f){aacc[2 * p], aacc[2 * p + 1]};
            v2f b = (v2f){bacc[2 * p], bacc[2 * p + 1]};
            v2f ab = __builtin_elementwise_max(a * b, kZero);  // NaN guard near diag
            v2f sq = (v2f){__builtin_amdgcn_sqrtf(ab.x), __builtin_amdgcn_sqrtf(ab.y)};
            v2f w  = __builtin_elementwise_fma(a + b, kM100, kOne);
            w = __builtin_elementwise_fma(sq, k200, w);
            w = __builtin_elementwise_max(w, kZero);
            racc[mi][p] = __builtin_elementwise_fma(w, vj2, racc[mi][p]);
            if (offd) cacc = __builtin_elementwise_fma(w, vi2[mi][p], cacc);
          }
        }
        if (offd) {  // column contribution: y[J] += S^T v_I (S symmetric)
          float c = cacc.x + cacc.y;
          c += __shfl_xor(c, 16);
          c += __shfl_xor(c, 32);
          if (lane < 16) atomicAdd(&vdst[j0 + tj * 16 + lane], c * RESCALE);
        }
      }

      // Row contribution: reduce across 16 columns, one atomic per row.
#pragma unroll
      for (int mi = 0; mi < MI; ++mi)
#pragma unroll
        for (int p = 0; p < 2; ++p) {
          float r0 = racc[mi][p].x, r1 = racc[mi][p].y;
          r0 += __shfl_xor(r0, 1); r0 += __shfl_xor(r0, 2);
          r0 += __shfl_xor(r0, 4); r0 += __shfl_xor(r0, 8);
          r1 += __shfl_xor(r1, 1); r1 += __shfl_xor(r1, 2);
          r1 += __shfl_xor(r1, 4); r1 += __shfl_xor(r1, 8);
          if (col == 0) {
            const int row = i0 + wv * 32 + mi * 16 + kb4 + 2 * p;
            atomicAdd(&vdst[row],     r0 * RESCALE);
            atomicAdd(&vdst[row + 1], r1 * RESCALE);
          }
        }
    }

    // SIGNAL: one release store per block (no RMW, no convoy).
    __threadfence();     // drain this block's atomics to the coherent point
    __syncthreads();
    if (t == 0)
      __hip_atomic_store(&flags[it * FSTRIDE + bid], 1u, __ATOMIC_RELEASE,
                         __HIP_MEMORY_SCOPE_AGENT);
  }

  // Finalize: blocks 0..23 wait for everyone's iter-9, then normalize.
  if (bid < NPTS / 256) {
    wait_iter(flags + (NITER - 1) * FSTRIDE);
    const float* va = vbase + NITER * VSTRIDE;
    float ss = 0.0f;
    for (int k2 = t; k2 < NPTS; k2 += 256) {
      float x = va[k2];
      ss = fmaf(x, x, ss);
    }
    for (int off = 32; off > 0; off >>= 1) ss += __shfl_down(ss, off, 64);
    __syncthreads();
    if ((t & 63) == 0) shf[t >> 6] = ss;
    __syncthreads();
    float tot = shf[0] + shf[1] + shf[2] + shf[3];
    float inv = 1.0f / (sqrtf(tot) + 1e-6f);
    const int i = bid * 256 + t;
    out[i] = va[i] * inv;
  }
}

extern "C" void kernel_launch(void* const* d_in, const int* in_sizes, int n_in,
                              void* d_out, int out_size, void* d_ws, size_t ws_size,
                              hipStream_t stream) {
  const float* p2 = (const float*)d_in[0];   // 6144 x 2, float32
  const float* p3 = (const float*)d_in[1];   // 6144 x 3, float32
  float* out = (float*)d_out;                // 6144, float32

  float* w = (float*)d_ws;
  float* vbase = w;                          // 11 x 8192 floats
  u32*   flags = (u32*)(w + NVF);            // 10 x 640 flags

  const int prep_elems = NVF + NFLAG;
  prep_kernel<<<(prep_elems + 255) / 256, 256, 0, stream>>>(vbase, flags);
  sc2_kernel<<<GRID, 256, 0, stream>>>(p2, p3, vbase, flags, out);
}